// Round 2
// baseline (26756.012 us; speedup 1.0000x reference)
//
#include <hip/hip_runtime.h>
#include <hip/hip_fp16.h>

typedef _Float16 h2_t __attribute__((ext_vector_type(2)));
typedef unsigned int u32x4 __attribute__((ext_vector_type(4)));

#define KEXP 2.8853900817779268f  // 2/ln2

__device__ __forceinline__ float fdot2(unsigned int a, unsigned int b, float c) {
#if __has_builtin(__builtin_amdgcn_fdot2)
    return __builtin_amdgcn_fdot2(__builtin_bit_cast(h2_t, a), __builtin_bit_cast(h2_t, b), c, false);
#else
    h2_t ha = __builtin_bit_cast(h2_t, a), hb = __builtin_bit_cast(h2_t, b);
    return c + (float)ha[0]*(float)hb[0] + (float)ha[1]*(float)hb[1];
#endif
}

__device__ __forceinline__ unsigned int pk16(float a, float b) {
    auto h = __builtin_amdgcn_cvt_pkrtz(a, b);
    return __builtin_bit_cast(unsigned int, h);
}

__device__ __forceinline__ float rcp_(float x) {
#if __has_builtin(__builtin_amdgcn_rcpf)
    return __builtin_amdgcn_rcpf(x);
#else
    return 1.0f / x;
#endif
}

__device__ __forceinline__ float sigm(float x) { return rcp_(1.0f + __expf(-x)); }
__device__ __forceinline__ float tanh_(float x) {
    float e = __expf(2.0f * x);
    return 1.0f - 2.0f * rcp_(e + 1.0f);
}

// r2 = 1/(1+2^s) per f16 lane pair
__device__ __forceinline__ unsigned int rcp1p2exp(unsigned int s) {
    __half2 e = h2exp2(__builtin_bit_cast(__half2, s));
    __half2 d = __hadd2(e, __float2half2_rn(1.0f));
    return __builtin_bit_cast(unsigned int, h2rcp(d));
}
__device__ __forceinline__ unsigned int hadd2u(unsigned int a, unsigned int b) {
    return __builtin_bit_cast(unsigned int,
        __hadd2(__builtin_bit_cast(__half2, a), __builtin_bit_cast(__half2, b)));
}

// ---- prep: pack weights to f16, layout [k8][j]: u32x4 = 8 halves of row j, cols 8k8..8k8+7 ----
__global__ __launch_bounds__(256) void prep_kernel(
    const float* __restrict__ encWhh, const float* __restrict__ decWih,
    const float* __restrict__ decWhh, const float* __restrict__ W2w,
    u32x4* __restrict__ We8, u32x4* __restrict__ Wi8, u32x4* __restrict__ Wh8, u32x4* __restrict__ W28)
{
    int id = blockIdx.x * 256 + threadIdx.x;
    if (id < 3 * 32768) {
        int mat = id >> 15, local = id & 32767;
        int j = local & 1023, k8 = local >> 10;
        const float* src = mat == 0 ? encWhh : (mat == 1 ? decWih : decWhh);
        u32x4* dst = mat == 0 ? We8 : (mat == 1 ? Wi8 : Wh8);
        const float* p = src + (size_t)j * 256 + k8 * 8;
        float4 a = *(const float4*)p; float4 c = *(const float4*)(p + 4);
        u32x4 v; v[0] = pk16(a.x, a.y); v[1] = pk16(a.z, a.w);
        v[2] = pk16(c.x, c.y); v[3] = pk16(c.z, c.w);
        dst[k8 * 1024 + j] = v;
    } else {
        int local = id - 3 * 32768;
        if (local < 8192) {
            int m = local & 255, k8 = local >> 8;
            const float* p = W2w + (size_t)m * 256 + k8 * 8;
            float4 a = *(const float4*)p; float4 c = *(const float4*)(p + 4);
            u32x4 v; v[0] = pk16(a.x, a.y); v[1] = pk16(a.z, a.w);
            v[2] = pk16(c.x, c.y); v[3] = pk16(c.z, c.w);
            W28[k8 * 256 + m] = v;
        }
    }
}

// ---- GEMM: C[M][N](f16) = (A[M][256] * Bw[N][256]^T + bias) * scale ----
template<int A_IS_F16>
__global__ __launch_bounds__(256) void gemm_kernel(
    const void* __restrict__ A_, const float* __restrict__ Bw,
    const float* __restrict__ bias, unsigned short* __restrict__ C, int N, float scale)
{
    __shared__ float As[16][68];
    __shared__ float Bs[16][132];
    const int t = threadIdx.x;
    const int row0 = blockIdx.y * 64, col0 = blockIdx.x * 128;
    const int ty = t >> 4, tx = t & 15;
    const int lm = t & 63, lkq = t >> 6;
    const int ln = t & 127, lkq2 = t >> 7;
    float acc[4][8] = {};
    for (int k0 = 0; k0 < 256; k0 += 16) {
        float4 av;
        if constexpr (A_IS_F16) {
            const unsigned short* A = (const unsigned short*)A_;
            uint2 ha = *(const uint2*)(A + (size_t)(row0 + lm) * 256 + k0 + lkq * 4);
            h2_t h0 = __builtin_bit_cast(h2_t, ha.x);
            h2_t h1 = __builtin_bit_cast(h2_t, ha.y);
            av = make_float4((float)h0[0], (float)h0[1], (float)h1[0], (float)h1[1]);
        } else {
            av = *(const float4*)((const float*)A_ + (size_t)(row0 + lm) * 256 + k0 + lkq * 4);
        }
        const float* bp = Bw + (size_t)(col0 + ln) * 256 + k0 + lkq2 * 8;
        float4 bv0 = *(const float4*)bp;
        float4 bv1 = *(const float4*)(bp + 4);
        __syncthreads();
        As[lkq * 4 + 0][lm] = av.x;
        As[lkq * 4 + 1][lm] = av.y;
        As[lkq * 4 + 2][lm] = av.z;
        As[lkq * 4 + 3][lm] = av.w;
        Bs[lkq2 * 8 + 0][ln] = bv0.x;
        Bs[lkq2 * 8 + 1][ln] = bv0.y;
        Bs[lkq2 * 8 + 2][ln] = bv0.z;
        Bs[lkq2 * 8 + 3][ln] = bv0.w;
        Bs[lkq2 * 8 + 4][ln] = bv1.x;
        Bs[lkq2 * 8 + 5][ln] = bv1.y;
        Bs[lkq2 * 8 + 6][ln] = bv1.z;
        Bs[lkq2 * 8 + 7][ln] = bv1.w;
        __syncthreads();
        #pragma unroll
        for (int kk = 0; kk < 16; ++kk) {
            float4 a = *(float4*)&As[kk][ty * 4];
            float4 b0 = *(float4*)&Bs[kk][tx * 8];
            float4 b1 = *(float4*)&Bs[kk][tx * 8 + 4];
            float ar[4] = {a.x, a.y, a.z, a.w};
            float br[8] = {b0.x, b0.y, b0.z, b0.w, b1.x, b1.y, b1.z, b1.w};
            #pragma unroll
            for (int i = 0; i < 4; ++i)
                #pragma unroll
                for (int j = 0; j < 8; ++j)
                    acc[i][j] = fmaf(ar[i], br[j], acc[i][j]);
        }
    }
    float bv[8];
    #pragma unroll
    for (int j = 0; j < 8; ++j) bv[j] = bias[col0 + tx * 8 + j];
    #pragma unroll
    for (int i = 0; i < 4; ++i) {
        unsigned int w0 = pk16((acc[i][0] + bv[0]) * scale, (acc[i][1] + bv[1]) * scale);
        unsigned int w1 = pk16((acc[i][2] + bv[2]) * scale, (acc[i][3] + bv[3]) * scale);
        unsigned int w2 = pk16((acc[i][4] + bv[4]) * scale, (acc[i][5] + bv[5]) * scale);
        unsigned int w3 = pk16((acc[i][6] + bv[6]) * scale, (acc[i][7] + bv[7]) * scale);
        *(uint4*)(C + (size_t)(row0 + ty * 4 + i) * N + col0 + tx * 8) = make_uint4(w0, w1, w2, w3);
    }
}

// ---- encoder: 1 block per batch; emits enc_h [b][s][h] f16 and encP [b][s2][h] packed s-pairs ----
__global__ __launch_bounds__(1024) void encoder_kernel(
    const unsigned short* __restrict__ Xproj, const u32x4* __restrict__ We8,
    float* __restrict__ hfin, float* __restrict__ cfin,
    unsigned short* __restrict__ enc_h, unsigned int* __restrict__ encP)
{
    const int b = blockIdx.x, t = threadIdx.x;
    __shared__ __align__(16) float zs[1024];
    __shared__ __align__(16) unsigned int hh2[128];
    if (t < 128) hh2[t] = 0u;
    float c_reg = 0.f, hprev = 0.f, hcur = 0.f;
    __syncthreads();
    const unsigned short* xp = Xproj + (size_t)b * 512 * 1024 + t;
    for (int step = 0; step < 512; ++step) {
        float acc = __half2float(__ushort_as_half(__builtin_nontemporal_load(xp)));
        #pragma unroll 8
        for (int k8 = 0; k8 < 32; ++k8) {
            u32x4 wv = We8[k8 * 1024 + t];
            u32x4 hv = *(const u32x4*)&hh2[k8 * 4];
            acc = fdot2(wv[0], hv[0], acc); acc = fdot2(wv[1], hv[1], acc);
            acc = fdot2(wv[2], hv[2], acc); acc = fdot2(wv[3], hv[3], acc);
        }
        zs[t] = acc;
        __syncthreads();
        if (t < 256) {
            float ig = sigm(zs[t]), fg = sigm(zs[t + 256]);
            float gg = tanh_(zs[t + 512]), og = sigm(zs[t + 768]);
            c_reg = fg * c_reg + ig * gg;
            float h = og * tanh_(c_reg);
            float hnb = __shfl_down(h, 1);
            if (!(t & 1)) hh2[t >> 1] = pk16(h, hnb);
            __builtin_nontemporal_store(__half_as_ushort(__float2half_rn(h)),
                                        enc_h + (size_t)(b * 512 + step) * 256 + t);
            if (step & 1)
                __builtin_nontemporal_store(pk16(hprev, h),
                                            encP + (size_t)b * 65536 + (size_t)(step >> 1) * 256 + t);
            hprev = h; hcur = h;
        }
        __syncthreads();
        xp += 1024;
    }
    if (t < 256) { hfin[b * 256 + t] = hcur; cfin[b * 256 + t] = c_reg; }
}

// ---- decoder: 1 block per batch, 512-step pointer loop, wave-coalesced streams ----
__global__ __launch_bounds__(1024) void decoder_kernel(
    const u32x4* __restrict__ Wi8, const u32x4* __restrict__ Wh8, const u32x4* __restrict__ W28,
    const float* __restrict__ dec_b, const float* __restrict__ W2b, const float* __restrict__ vtw,
    const float* __restrict__ hfin, const float* __restrict__ cfin,
    const unsigned short* __restrict__ proj_h, const unsigned int* __restrict__ encP,
    float* __restrict__ out)
{
    const int b = blockIdx.x, t = threadIdx.x;
    const int lane = t & 63, w = t >> 6;
    __shared__ __align__(16) float zs[1024];
    __shared__ __align__(16) unsigned int hh2[128];
    __shared__ __align__(16) unsigned int din2[128];
    __shared__ __align__(16) unsigned int qp2[128];
    __shared__ __align__(16) unsigned int mv2u[128];
    __shared__ __align__(16) unsigned int p2[256];
    __shared__ float wredm[8], wreds[8], svtS;

    const float bj = dec_b[t];
    const float w2b_r = (t < 256) ? W2b[t] : 0.f;
    float c_reg = (t < 256) ? cfin[b * 256 + t] : 0.f;
    if (t < 128) { din2[t] = 0u; mv2u[t] = pk16(-2.f * vtw[2 * t], -2.f * vtw[2 * t + 1]); }
    if (t < 256) zs[t] = vtw[t];
    __syncthreads();
    if (t < 64) {
        float v = zs[t] + zs[t + 64] + zs[t + 128] + zs[t + 192];
        #pragma unroll
        for (int off = 1; off < 64; off <<= 1) v += __shfl_xor(v, off);
        if (t == 0) svtS = v;
    }
    if (t < 256) {
        float h0 = hfin[b * 256 + t];
        float hnb = __shfl_down(h0, 1);
        if (!(t & 1)) hh2[t >> 1] = pk16(h0, hnb);
    }
    __syncthreads();
    const float svt = svtS;
    const u32x4 mvv = *(const u32x4*)&mv2u[(lane & 31) * 4];
    const int hb4 = (lane & 31) * 4;
    const u32x4* projw = (const u32x4*)(proj_h + (size_t)b * 131072 + (size_t)w * 8192);
    const unsigned int* encPb = encP + (size_t)b * 65536;
    const int hF = t & 255, slF = t >> 8;
    const unsigned int* fb = encPb + (size_t)(slF * 64) * 256 + hF;
    float* outp = out + (size_t)b * 262144;

    for (int step = 0; step < 512; ++step) {
        // ---- A: z = dec_b + Wih*din + Whh*h ----
        float acc = bj;
        #pragma unroll 8
        for (int k8 = 0; k8 < 32; ++k8) {
            u32x4 wiv = Wi8[k8 * 1024 + t];
            u32x4 div = *(const u32x4*)&din2[k8 * 4];
            acc = fdot2(wiv[0], div[0], acc); acc = fdot2(wiv[1], div[1], acc);
            acc = fdot2(wiv[2], div[2], acc); acc = fdot2(wiv[3], div[3], acc);
            u32x4 whv = Wh8[k8 * 1024 + t];
            u32x4 hv = *(const u32x4*)&hh2[k8 * 4];
            acc = fdot2(whv[0], hv[0], acc); acc = fdot2(whv[1], hv[1], acc);
            acc = fdot2(whv[2], hv[2], acc); acc = fdot2(whv[3], hv[3], acc);
        }
        zs[t] = acc;
        __syncthreads();                                          // 1
        // ---- B: gates ----
        if (t < 256) {
            float ig = sigm(zs[t]), fg = sigm(zs[t + 256]);
            float gg = tanh_(zs[t + 512]), og = sigm(zs[t + 768]);
            c_reg = fg * c_reg + ig * gg;
            float h = og * tanh_(c_reg);
            float hnb = __shfl_down(h, 1);
            if (!(t & 1)) hh2[t >> 1] = pk16(h, hnb);
        }
        __syncthreads();                                          // 2
        // ---- C: q partials (all 1024 threads, 4 k-slices) ----
        {
            float qa = 0.f;
            #pragma unroll
            for (int i = 0; i < 8; ++i) {
                int k8 = slF * 8 + i;
                u32x4 wv = W28[k8 * 256 + hF];
                u32x4 hv = *(const u32x4*)&hh2[k8 * 4];
                qa = fdot2(wv[0], hv[0], qa); qa = fdot2(wv[1], hv[1], qa);
                qa = fdot2(wv[2], hv[2], qa); qa = fdot2(wv[3], hv[3], qa);
            }
            zs[t] = qa;
        }
        __syncthreads();                                          // 3
        if (t < 256) {
            float q = (w2b_r + zs[t] + zs[t + 256] + zs[t + 512] + zs[t + 768]) * KEXP;
            float qnx = __shfl_down(q, 1);
            if (!(t & 1)) qp2[t >> 1] = pk16(q, qnx);
        }
        __syncthreads();                                          // 4
        // ---- D: u[s] = svt + sum_h (-2vt)/(1+2^(pScaled+qScaled)) ; 2 rows per wave instr ----
        {
            const u32x4 qh = *(const u32x4*)&qp2[hb4];
            u32x4 pv[16];
            #pragma unroll
            for (int i = 0; i < 16; ++i) pv[i] = __builtin_nontemporal_load(projw + i * 64 + lane);
            #pragma unroll
            for (int i = 0; i < 16; ++i) {
                float up = 0.f;
                up = fdot2(mvv[0], rcp1p2exp(hadd2u(pv[i][0], qh[0])), up);
                up = fdot2(mvv[1], rcp1p2exp(hadd2u(pv[i][1], qh[1])), up);
                up = fdot2(mvv[2], rcp1p2exp(hadd2u(pv[i][2], qh[2])), up);
                up = fdot2(mvv[3], rcp1p2exp(hadd2u(pv[i][3], qh[3])), up);
                #pragma unroll
                for (int off = 1; off < 32; off <<= 1) up += __shfl_xor(up, off);
                if (!(lane & 31)) zs[w * 32 + 2 * i + (lane >> 5)] = up + svt;
            }
        }
        __syncthreads();                                          // 5
        // ---- softmax over s (waves 0-7) ----
        float e = 0.f, rs;
        {
            float v = (t < 512) ? zs[t] : 0.f;
            if (t < 512) {
                float wm = v;
                #pragma unroll
                for (int off = 1; off < 64; off <<= 1) wm = fmaxf(wm, __shfl_xor(wm, off));
                if (lane == 0) wredm[w] = wm;
            }
            __syncthreads();                                      // 6
            if (t < 512) {
                float gmax = wredm[0];
                #pragma unroll
                for (int k = 1; k < 8; ++k) gmax = fmaxf(gmax, wredm[k]);
                e = __expf(v - gmax);
                float ws = e;
                #pragma unroll
                for (int off = 1; off < 64; off <<= 1) ws += __shfl_xor(ws, off);
                if (lane == 0) wreds[w] = ws;
                float enx = __shfl_down(e, 1);
                if (!(t & 1)) p2[t >> 1] = pk16(e, enx);
            }
            __syncthreads();                                      // 7
            float gs = wreds[0];
            #pragma unroll
            for (int k = 1; k < 8; ++k) gs += wreds[k];
            rs = rcp_(gs);
            if (t < 512)
                __builtin_nontemporal_store(e * rs, outp + (size_t)step * 512 + t);
        }
        // ---- F: din[h] = (sum_s e_s enc[s][h]) / sum(e) ; coalesced over h ----
        {
            float fa = 0.f;
            #pragma unroll 16
            for (int k = 0; k < 64; ++k) {
                unsigned int ev = __builtin_nontemporal_load(fb + k * 256);
                fa = fdot2(ev, p2[slF * 64 + k], fa);
            }
            zs[t] = fa;
        }
        __syncthreads();                                          // 8
        if (t < 256) {
            float dval = (zs[t] + zs[t + 256] + zs[t + 512] + zs[t + 768]) * rs;
            float dnx = __shfl_down(dval, 1);
            if (!(t & 1)) din2[t >> 1] = pk16(dval, dnx);
        }
        __syncthreads();                                          // 9
    }
}

extern "C" void kernel_launch(void* const* d_in, const int* in_sizes, int n_in,
                              void* d_out, int out_size, void* d_ws, size_t ws_size,
                              hipStream_t stream) {
    const float* x      = (const float*)d_in[0];
    const float* encWih = (const float*)d_in[1];
    const float* encWhh = (const float*)d_in[2];
    const float* enc_b  = (const float*)d_in[3];
    const float* decWih = (const float*)d_in[4];
    const float* decWhh = (const float*)d_in[5];
    const float* dec_bp = (const float*)d_in[6];
    const float* W1w    = (const float*)d_in[7];
    const float* W1b    = (const float*)d_in[8];
    const float* W2w    = (const float*)d_in[9];
    const float* W2bp   = (const float*)d_in[10];
    const float* vtw    = (const float*)d_in[11];

    char* ws = (char*)d_ws;
    u32x4* We8 = (u32x4*)(ws);
    u32x4* Wi8 = (u32x4*)(ws + 524288);
    u32x4* Wh8 = (u32x4*)(ws + 1048576);
    u32x4* W28 = (u32x4*)(ws + 1572864);
    unsigned short* enc_h  = (unsigned short*)(ws + 1703936);
    unsigned int*   encP   = (unsigned int*)(ws + 35258368);
    unsigned short* proj_h = (unsigned short*)(ws + 68812800);
    float* hfin = (float*)(ws + 102367232);
    float* cfin = (float*)(ws + 102498304);

    unsigned short* Xproj = (unsigned short*)d_out;  // f16 [65536][1024], consumed before decoder overwrites

    prep_kernel<<<416, 256, 0, stream>>>(encWhh, decWih, decWhh, W2w, We8, Wi8, Wh8, W28);
    gemm_kernel<0><<<dim3(8, 1024), 256, 0, stream>>>(x, encWih, enc_b, Xproj, 1024, 1.0f);
    encoder_kernel<<<128, 1024, 0, stream>>>(Xproj, We8, hfin, cfin, enc_h, encP);
    gemm_kernel<1><<<dim3(2, 1024), 256, 0, stream>>>(enc_h, W1w, W1b, proj_h, 256, KEXP);
    decoder_kernel<<<128, 1024, 0, stream>>>(Wi8, Wh8, W28, dec_bp, W2bp, vtw,
                                             hfin, cfin, proj_h, encP, (float*)d_out);
}